// Round 10
// baseline (317.286 us; speedup 1.0000x reference)
//
#include <hip/hip_runtime.h>

// vid [T,C,H,W] fp32, patches [N,1,C,7,7] fp32, queryInds [N,3]=(t,h,w) int32.
constexpr int T_ = 16, C_ = 3, H_ = 512, W_ = 512, PS_ = 7;
constexpr int PATCH_ELEMS = C_ * PS_ * PS_;      // 147
constexpr int TILE  = 32;
constexpr int HALO  = PS_ - 1;                   // 6
constexpr int NTH = H_ / TILE, NTW = W_ / TILE;  // 16 x 16
constexpr int NBINS = T_ * NTH * NTW;            // 4096
constexpr int ASTR = 36;                         // padded acc row stride (16B align)
constexpr int ACC_PER_C  = TILE * ASTR;          // 1152
constexpr int ACC_FLOATS = C_ * ACC_PER_C;       // 3456 (13.8 KB)
constexpr int INTERIOR   = C_ * TILE * TILE;     // 3072
constexpr int NREP = 8;                          // counter replicas (~1 per XCD)
constexpr int CAPS = 32;                         // per-replica list capacity (mean ~8)
constexpr int RMAX = 4 * NREP * CAPS;            // 1024 worst-case merged records
constexpr int BTHR = 192;                        // 3 waves = 3 channels

// ws layout (bytes)
constexpr size_t OFF_COUNTS = 0;                                   // 4096*8 ints (128 KB)
constexpr size_t OFF_LIST   = (size_t)NBINS * NREP * 4;
constexpr size_t WS_NEEDED  = OFF_LIST + (size_t)NBINS * NREP * CAPS * 4;  // ~4.3 MB

__global__ void zero_counts_kernel(int* counts) {
    counts[blockIdx.x * 1024 + threadIdx.x] = 0;   // 32 blocks x 1024 = 32768 ints
}

// Bin by corner tile into replica (blockIdx & 7): blocks round-robin XCDs, so
// each replica's counter lines stay (mostly) XCD-local -> no cross-XCD atomic
// ping-pong, and same-address collisions drop 64 -> ~8.
// Record packed (n, local_y, local_x): n<<10 | ly<<5 | lx.
__global__ void scatter_kernel(const int* __restrict__ q, int* __restrict__ counts,
                               int* __restrict__ list, int nq) {
    int n = blockIdx.x * 256 + threadIdx.x;
    if (n >= nq) return;
    int rep = blockIdx.x & (NREP - 1);
    int t = q[3 * n], h = q[3 * n + 1], w = q[3 * n + 2];
    int bin = (t * NTH + (h >> 5)) * NTW + (w >> 5);
    int slot = bin * NREP + rep;
    int pos = atomicAdd(counts + slot, 1);
    if (pos < CAPS) list[slot * CAPS + pos] = (n << 10) | ((h & 31) << 5) | (w & 31);
}

// One block per (t, 32x32 tile). Gathers ALL patches overlapping its EXACT
// 32x32 output region: own bin + filtered up/left/diag neighbor bins (all 8
// replica segments each). Every output pixel computed fully here and written
// exactly once: out = vid + acc, plain float4 — no halo pass, no atomics.
// Wave c owns channel-c acc plane -> race-free LDS RMW (R1 invariant).
// Merged record coords rebased to this tile: ry,rx in [-6,32), stored +6.
__global__ __launch_bounds__(BTHR, 6) void accum_kernel(
    const float* __restrict__ patches, const int* __restrict__ counts,
    const int* __restrict__ list, const float* __restrict__ vid,
    float* __restrict__ out) {
    __shared__ alignas(16) float acc[ACC_FLOATS];
    __shared__ int recs[RMAX];
    __shared__ int nrec_sh;
    const int bin = blockIdx.x;
    const int t = bin >> 8;
    const int ti = (bin >> 4) & 15, tj = bin & 15;
    const int h0 = ti * TILE, w0 = tj * TILE;
    const int tid = threadIdx.x;
    const int lane = tid & 63, wid = tid >> 6;   // 3 waves; wid = channel

    for (int i = tid; i < ACC_FLOATS; i += BTHR) acc[i] = 0.f;
    if (tid == 0) nrec_sh = 0;
    __syncthreads();

    // ---- merge-filter 4 source bins x 8 replica segments ----
    {
        const int srcs[4][2] = {{0, 0}, {-1, 0}, {0, -1}, {-1, -1}};
#pragma unroll
        for (int s = 0; s < 4; ++s) {
            int di = srcs[s][0], dj = srcs[s][1];
            if ((ti + di) < 0 || (tj + dj) < 0) continue;
            int sbin = bin + di * NTW + dj;
            for (int r = 0; r < NREP; ++r) {
                int slot = sbin * NREP + r;
                int cs = counts[slot];
                if (cs > CAPS) cs = CAPS;
                for (int k = tid; k < cs; k += BTHR) {
                    int rr = list[slot * CAPS + k];
                    int ry = ((rr >> 5) & 31) + di * TILE;   // in [-32, 32)
                    int rx = (rr & 31) + dj * TILE;
                    if (ry >= -HALO && rx >= -HALO) {        // footprint reaches tile
                        int pos = atomicAdd(&nrec_sh, 1);
                        if (pos < RMAX)
                            recs[pos] = ((rr >> 10) << 12) | ((ry + 6) << 6) | (rx + 6);
                    }
                }
            }
        }
    }
    __syncthreads();
    int nrec = nrec_sh;
    if (nrec > RMAX) nrec = RMAX;

    // ---- accumulate: wave = channel, depth-8 register pipeline ----
    {
        const int c = wid;
        const bool act = lane < PS_ * PS_;               // 49 active lanes
        const int dy = lane / PS_, dx = lane % PS_;      // patch-element coords
        float* __restrict__ ac = acc + c * ACC_PER_C;
        const float* __restrict__ pc = patches + c * (PS_ * PS_);

        float v0=0,v1=0,v2=0,v3=0,v4=0,v5=0,v6=0,v7=0;
        int o0=-1,o1=-1,o2=-1,o3=-1,o4=-1,o5=-1,o6=-1,o7=-1;
#define LDR(vv,oo,ii) { int rr = recs[(ii)]; \
        int ty = ((rr >> 6) & 63) - 6 + dy; \
        int tx = (rr & 63) - 6 + dx; \
        bool ok = act && ((unsigned)ty < (unsigned)TILE) && ((unsigned)tx < (unsigned)TILE); \
        oo = ok ? ty * ASTR + tx : -1; \
        vv = act ? pc[(size_t)((unsigned)rr >> 12) * PATCH_ELEMS + lane] : 0.f; }
        if (0 < nrec) LDR(v0,o0, 0)
        if (1 < nrec) LDR(v1,o1, 1)
        if (2 < nrec) LDR(v2,o2, 2)
        if (3 < nrec) LDR(v3,o3, 3)
        if (4 < nrec) LDR(v4,o4, 4)
        if (5 < nrec) LDR(v5,o5, 5)
        if (6 < nrec) LDR(v6,o6, 6)
        if (7 < nrec) LDR(v7,o7, 7)
        for (int p = 0; p < nrec; p += 8) {
            float x0=v0,x1=v1,x2=v2,x3=v3,x4=v4,x5=v5,x6=v6,x7=v7;
            int q0=o0,q1=o1,q2=o2,q3=o3,q4=o4,q5=o5,q6=o6,q7=o7;
            int qq = p + 8;
            o0=-1;o1=-1;o2=-1;o3=-1;o4=-1;o5=-1;o6=-1;o7=-1;
            if (qq     < nrec) LDR(v0,o0, qq)
            if (qq + 1 < nrec) LDR(v1,o1, qq+1)
            if (qq + 2 < nrec) LDR(v2,o2, qq+2)
            if (qq + 3 < nrec) LDR(v3,o3, qq+3)
            if (qq + 4 < nrec) LDR(v4,o4, qq+4)
            if (qq + 5 < nrec) LDR(v5,o5, qq+5)
            if (qq + 6 < nrec) LDR(v6,o6, qq+6)
            if (qq + 7 < nrec) LDR(v7,o7, qq+7)
            if (q0 >= 0) ac[q0] += x0;
            if (q1 >= 0 && p + 1 < nrec) ac[q1] += x1;
            if (q2 >= 0 && p + 2 < nrec) ac[q2] += x2;
            if (q3 >= 0 && p + 3 < nrec) ac[q3] += x3;
            if (q4 >= 0 && p + 4 < nrec) ac[q4] += x4;
            if (q5 >= 0 && p + 5 < nrec) ac[q5] += x5;
            if (q6 >= 0 && p + 6 < nrec) ac[q6] += x6;
            if (q7 >= 0 && p + 7 < nrec) ac[q7] += x7;
        }
#undef LDR
    }
    __syncthreads();

    // ---- epilogue: out = vid + acc for the exact 32x32 tile, float4 ----
    const size_t obase = (size_t)t * C_ * H_ * W_;
    for (int i = tid; i < INTERIOR / 4; i += BTHR) {   // 768 float4
        int cc = i >> 8, rem = i & 255, y = rem >> 3, x4 = rem & 7;
        size_t g = obase + (size_t)cc * (H_ * W_) + (size_t)(h0 + y) * W_ + (w0 + x4 * 4);
        const float4 vv = *reinterpret_cast<const float4*>(vid + g);
        const float4 aa = *reinterpret_cast<const float4*>(
            &acc[cc * ACC_PER_C + y * ASTR + x4 * 4]);
        float4 r; r.x = vv.x + aa.x; r.y = vv.y + aa.y; r.z = vv.z + aa.z; r.w = vv.w + aa.w;
        *reinterpret_cast<float4*>(out + g) = r;
    }
}

// ---- fallback (round-1 path) if ws too small ----
__global__ void scatter_add_kernel(const float* __restrict__ patches,
                                   const int* __restrict__ qinds,
                                   float* __restrict__ out, int total) {
    int tid = blockIdx.x * blockDim.x + threadIdx.x;
    if (tid >= total) return;
    int n = tid / PATCH_ELEMS;
    int r = tid - n * PATCH_ELEMS;
    int c = r / (PS_ * PS_);
    int rr = r - c * (PS_ * PS_);
    int ih = rr / PS_, iw = rr - ih * PS_;
    int t = qinds[n * 3 + 0], h = qinds[n * 3 + 1], w = qinds[n * 3 + 2];
    int out_idx = ((t * C_ + c) * H_ + (h + ih)) * W_ + (w + iw);
    atomicAdd(out + out_idx, patches[tid]);
}

extern "C" void kernel_launch(void* const* d_in, const int* in_sizes, int n_in,
                              void* d_out, int out_size, void* d_ws, size_t ws_size,
                              hipStream_t stream) {
    const float* vid     = (const float*)d_in[0];
    const float* patches = (const float*)d_in[1];
    const int*   qinds   = (const int*)d_in[2];
    float*       out     = (float*)d_out;
    const int nq = in_sizes[2] / 3;

    if (ws_size < WS_NEEDED) {  // safety fallback
        hipMemcpyAsync(out, vid, (size_t)out_size * sizeof(float),
                       hipMemcpyDeviceToDevice, stream);
        int total = nq * PATCH_ELEMS;
        scatter_add_kernel<<<(total + 255) / 256, 256, 0, stream>>>(patches, qinds, out, total);
        return;
    }

    char* ws = (char*)d_ws;
    int* counts = (int*)(ws + OFF_COUNTS);
    int* list   = (int*)(ws + OFF_LIST);

    zero_counts_kernel<<<NBINS * NREP / 1024, 1024, 0, stream>>>(counts);
    scatter_kernel<<<(nq + 255) / 256, 256, 0, stream>>>(qinds, counts, list, nq);
    accum_kernel<<<NBINS, BTHR, 0, stream>>>(patches, counts, list, vid, out);
}